// Round 6
// baseline (321.639 us; speedup 1.0000x reference)
//
#include <hip/hip_runtime.h>

#define NPTS  65536
#define NNEI  32
#define NKP   15
#define INF   64
#define OUTF  128
#define PPB   16            // points per block
#define KT_N  32            // 1024 padded k-dims / 32 (pad kp=15: w=0, W=0)
#define INV_KPE 41.666666666666664f
#define BN_EPS 1e-6f
#define NEG_SLOPE 0.1f

typedef __attribute__((ext_vector_type(8))) short  bf16x8;
typedef __attribute__((ext_vector_type(4))) float  f32x4;

// device-global scratch (no assumptions about ws_size)
__device__ unsigned short g_Wp[KT_N * 8 * 64 * 8];     // 256 KB, MFMA B-frag layout, k-dim i = chan*16+kp
__device__ unsigned short g_featb[NPTS * INF];         // 8 MB, features as bf16
__device__ float g_ssum[OUTF], g_ssq[OUTF], g_scale[OUTF], g_shift[OUTF];

__device__ __forceinline__ unsigned short f2b(float f) {
    union { float f; unsigned int i; } v; v.f = f;
    unsigned int x = v.i;
    return (unsigned short)((x + 0x7fffu + ((x >> 16) & 1u)) >> 16);   // RNE
}
__device__ __forceinline__ unsigned int pk2(float a, float b) {
    return (unsigned int)f2b(a) | ((unsigned int)f2b(b) << 16);
}
__device__ __forceinline__ bf16x8 mk8(unsigned int a, unsigned int b,
                                      unsigned int c, unsigned int d) {
    unsigned int t[4] = {a, b, c, d};
    bf16x8 r; __builtin_memcpy(&r, t, 16); return r;
}

// ---------------- Kernel 0: pack W -> bf16 B-frag (permuted k-enum), feat -> bf16, zero stats
__global__ __launch_bounds__(256) void pack_inputs(const float* __restrict__ W,
                                                   const float* __restrict__ feat) {
    const int b = blockIdx.x, t = threadIdx.x;
    if (b == 0) {
        if (t < OUTF)          g_ssum[t] = 0.0f;
        else if (t < 2 * OUTF) g_ssq[t - OUTF] = 0.0f;
    }
    if (b < 512) {                      // g_Wp: 131072 entries
        int id = b * 256 + t;
        int j  = id & 7;
        int ln = (id >> 3) & 63;
        int nt = (id >> 9) & 7;
        int kt = id >> 12;              // 0..31
        int i  = kt * 32 + ((ln >> 4) * 8) + j;   // padded k-dim, i = chan*16 + kp
        int kp = i & 15;
        int ch = i >> 4;
        int o  = nt * 16 + (ln & 15);
        g_Wp[id] = (kp < NKP) ? f2b(W[(kp * 64 + ch) * 128 + o]) : (unsigned short)0;
    } else {                            // feat: 1048576 float4s -> bf16 pairs
        int id = (b - 512) * 256 + t;
        const float4 v = ((const float4*)feat)[id];
        uint2 r; r.x = pk2(v.x, v.y); r.y = pk2(v.z, v.w);
        ((uint2*)g_featb)[id] = r;
    }
}

// ---------------- Kernel 1: fused KPConv (both stages MFMA) + fused BN partial stats
__global__ __launch_bounds__(256, 4) void kpconv_fused(
        const float* __restrict__ qp,    // [N][3]
        const float* __restrict__ sp,    // [N0][3]
        const int*   __restrict__ nbr,   // [N][32]
        const float* __restrict__ kp,    // [15][3]
        float*       __restrict__ out)   // [N][128] pre-BN x (f32)
{
    // weighted[pl][i] at ((g*PPB + (pl ^ ((g>>3)&7)))*8 + (i&7)), g = i>>3, bf16
    __shared__ __align__(16) unsigned short wlds[128 * PPB * 8];  // 32768 B
    __shared__ float dbuf[4][128][3];                             // 6144 B
    __shared__ int   ibuf[4][128];                                // 2048 B  -> total 40960 B

    const int tid  = threadIdx.x;
    const int lane = tid & 63;
    const int wv   = tid >> 6;
    const int q    = lane >> 4;
    const int c16  = lane & 15;
    const int gp0  = blockIdx.x * PPB + wv * 4;   // wave's first point

    // prologue: all 4 points' neighbor indices + diffs (all 64 lanes busy)
#pragma unroll
    for (int rep = 0; rep < 2; ++rep) {
        const int pt  = rep * 2 + (lane >> 5);
        const int m   = lane & 31;
        const int gpt = gp0 + pt;
        const int idx = nbr[gpt * NNEI + m];
        ibuf[wv][pt * 32 + m] = idx;
        dbuf[wv][pt * 32 + m][0] = sp[idx * 3 + 0] - qp[gpt * 3 + 0];
        dbuf[wv][pt * 32 + m][1] = sp[idx * 3 + 1] - qp[gpt * 3 + 1];
        dbuf[wv][pt * 32 + m][2] = sp[idx * 3 + 2] - qp[gpt * 3 + 2];
    }
    // kernel point per lane (c16 = kp index; 15 = pad -> w = 0)
    float kx, ky, kz;
    if (c16 < NKP) { kx = kp[c16 * 3]; ky = kp[c16 * 3 + 1]; kz = kp[c16 * 3 + 2]; }
    else           { kx = ky = kz = 1.0e6f; }
    // same-wave LDS in-order: no barrier needed before stage A

    // ---------------- Stage A: per point, weighted[16 kp][64 chan] via 4 MFMAs
    for (int pt = 0; pt < 4; ++pt) {
        const int pl = wv * 4 + pt;
        const int* ib = &ibuf[wv][pt * 32];

        // gather: 8 x dwordx2, lane gets chans 4*c16..4*c16+3 of row idx[q*8+j]
        uint2 d[8];
#pragma unroll
        for (int j = 0; j < 8; ++j) {
            const int idx = ib[q * 8 + j];
            d[j] = *(const uint2*)&g_featb[idx * INF + c16 * 4];
        }

        // A fragment: w[kp = c16][m = q*8+j]
        float w8[8];
#pragma unroll
        for (int j = 0; j < 8; ++j) {
            const int m = pt * 32 + q * 8 + j;
            const float ex = dbuf[wv][m][0] - kx;
            const float ey = dbuf[wv][m][1] - ky;
            const float ez = dbuf[wv][m][2] - kz;
            const float s  = ex * ex + ey * ey + ez * ez;
            const float w  = 1.0f - __builtin_amdgcn_sqrtf(s) * INV_KPE;
            w8[j] = (w > 0.0f) ? w : 0.0f;
        }
        const bf16x8 af = mk8(pk2(w8[0], w8[1]), pk2(w8[2], w8[3]),
                              pk2(w8[4], w8[5]), pk2(w8[6], w8[7]));

        // B fragments: nt-th ushort of each row's 4-chan group (v_perm-able bitops)
        f32x4 acc[4] = {{0.f,0.f,0.f,0.f},{0.f,0.f,0.f,0.f},
                        {0.f,0.f,0.f,0.f},{0.f,0.f,0.f,0.f}};
#pragma unroll
        for (int nt = 0; nt < 4; ++nt) {
            unsigned int dw[4];
#pragma unroll
            for (int p = 0; p < 4; ++p) {
                const unsigned int lo = (nt < 2) ? d[2 * p].x     : d[2 * p].y;
                const unsigned int hi = (nt < 2) ? d[2 * p + 1].x : d[2 * p + 1].y;
                dw[p] = (nt & 1) ? ((lo >> 16) | (hi & 0xffff0000u))
                                 : ((lo & 0xffffu) | (hi << 16));
            }
            acc[nt] = __builtin_amdgcn_mfma_f32_16x16x32_bf16(
                af, mk8(dw[0], dw[1], dw[2], dw[3]), acc[nt], 0, 0, 0);
        }

        // C: lane holds weighted[kp = q*4+r][chan = 4*c16+nt] -> i = (4c16+nt)*16 + 4q + r
        // 4 consecutive i per (nt): one ds_write_b64
#pragma unroll
        for (int nt = 0; nt < 4; ++nt) {
            uint2 pv;
            pv.x = pk2(acc[nt][0], acc[nt][1]);
            pv.y = pk2(acc[nt][2], acc[nt][3]);
            const int ibase = (c16 * 4 + nt) * 16 + q * 4;
            const int g   = ibase >> 3;
            const int off = ibase & 7;                 // = 4*(q&1)
            const int plx = pl ^ ((g >> 3) & 7);
            *(uint2*)&wlds[(g * PPB + plx) * 8 + off] = pv;
        }
    }
    __syncthreads();

    // ---------------- Stage B: [16 x 1024] @ [1024 x 128]; wave owns 2 n-tiles
    const int nt0 = wv * 2;
    f32x4 a00 = {0.f,0.f,0.f,0.f}, a01 = {0.f,0.f,0.f,0.f};

    for (int kt = 0; kt < KT_N; ++kt) {
        const int g   = kt * 4 + q;
        const int plx = c16 ^ ((g >> 3) & 7);          // A-frag row = point = c16
        const bf16x8 fa  = *(const bf16x8*)&wlds[(g * PPB + plx) * 8];
        const bf16x8 fb0 = *(const bf16x8*)&g_Wp[((kt * 8 + nt0) * 64 + lane) * 8];
        const bf16x8 fb1 = *(const bf16x8*)&g_Wp[((kt * 8 + nt0 + 1) * 64 + lane) * 8];
        a00 = __builtin_amdgcn_mfma_f32_16x16x32_bf16(fa, fb0, a00, 0, 0, 0);
        a01 = __builtin_amdgcn_mfma_f32_16x16x32_bf16(fa, fb1, a01, 0, 0, 0);
    }

    // epilogue: store pre-BN x + fused per-channel partial stats
    const int rb = blockIdx.x * PPB + q * 4;
    const int c0 = nt0 * 16 + c16;
    float s0 = 0.f, q0 = 0.f, s1 = 0.f, q1 = 0.f;
#pragma unroll
    for (int r = 0; r < 4; ++r) {
        const float v0 = a00[r], v1 = a01[r];
        out[(rb + r) * OUTF + c0]      = v0;
        out[(rb + r) * OUTF + c0 + 16] = v1;
        s0 += v0; q0 += v0 * v0;
        s1 += v1; q1 += v1 * v1;
    }
    s0 += __shfl_xor(s0, 16); s0 += __shfl_xor(s0, 32);
    q0 += __shfl_xor(q0, 16); q0 += __shfl_xor(q0, 32);
    s1 += __shfl_xor(s1, 16); s1 += __shfl_xor(s1, 32);
    q1 += __shfl_xor(q1, 16); q1 += __shfl_xor(q1, 32);
    if (lane < 16) {
        atomicAdd(&g_ssum[nt0 * 16 + lane],      s0);
        atomicAdd(&g_ssq [nt0 * 16 + lane],      q0);
        atomicAdd(&g_ssum[nt0 * 16 + 16 + lane], s1);
        atomicAdd(&g_ssq [nt0 * 16 + 16 + lane], q1);
    }
}

// ---------------- Kernel 2: per-channel scale/shift
__global__ void bn_scaleshift(const float* __restrict__ gamma,
                              const float* __restrict__ beta) {
    const int o = threadIdx.x;      // 128 threads
    const float inv_n = 1.0f / (float)NPTS;
    const float mean  = g_ssum[o] * inv_n;
    const float var   = g_ssq[o] * inv_n - mean * mean;
    const float sc    = gamma[o] * rsqrtf(var + BN_EPS);
    g_scale[o] = sc;
    g_shift[o] = beta[o] - mean * sc;
}

// ---------------- Kernel 3: in-place normalize + LeakyReLU (float4 / thread)
__global__ __launch_bounds__(256) void bn_norm(float* __restrict__ x) {
    const int id   = blockIdx.x * 256 + threadIdx.x;
    const int base = id * 4;
    const int o0   = base & 127;
    float4 v = *(const float4*)&x[base];
    const float4 sc = *(const float4*)&g_scale[o0];
    const float4 sf = *(const float4*)&g_shift[o0];
    float y0 = v.x * sc.x + sf.x;
    float y1 = v.y * sc.y + sf.y;
    float y2 = v.z * sc.z + sf.z;
    float y3 = v.w * sc.w + sf.w;
    y0 = (y0 >= 0.f) ? y0 : NEG_SLOPE * y0;
    y1 = (y1 >= 0.f) ? y1 : NEG_SLOPE * y1;
    y2 = (y2 >= 0.f) ? y2 : NEG_SLOPE * y2;
    y3 = (y3 >= 0.f) ? y3 : NEG_SLOPE * y3;
    float4 res = {y0, y1, y2, y3};
    *(float4*)&x[base] = res;
}

extern "C" void kernel_launch(void* const* d_in, const int* in_sizes, int n_in,
                              void* d_out, int out_size, void* d_ws, size_t ws_size,
                              hipStream_t stream) {
    const float* qp    = (const float*)d_in[0];
    const float* sp    = (const float*)d_in[1];
    const int*   nbr   = (const int*)d_in[2];
    const float* feat  = (const float*)d_in[3];
    const float* kp    = (const float*)d_in[4];
    const float* W     = (const float*)d_in[5];
    const float* gamma = (const float*)d_in[6];
    const float* beta  = (const float*)d_in[7];
    float* out = (float*)d_out;

    pack_inputs<<<512 + 4096, 256, 0, stream>>>(W, feat);
    kpconv_fused<<<NPTS / PPB, 256, 0, stream>>>(qp, sp, nbr, kp, out);
    bn_scaleshift<<<1, 128, 0, stream>>>(gamma, beta);
    bn_norm<<<(NPTS * OUTF) / (256 * 4), 256, 0, stream>>>(out);
}

// Round 7
// 190.354 us; speedup vs baseline: 1.6897x; 1.6897x over previous
//
#include <hip/hip_runtime.h>

#define NPTS  65536
#define NNEI  32
#define NKP   15
#define INF   64
#define OUTF  128
#define PPB   16            // points per block
#define KT_N  32            // 1024 padded k-dims / 32 (pad kp=15: w=0, W=0)
#define NSETS 64            // BN shadow accumulator sets
#define INV_KPE 41.666666666666664f
#define BN_EPS 1e-6f
#define NEG_SLOPE 0.1f

typedef __attribute__((ext_vector_type(8))) short  bf16x8;
typedef __attribute__((ext_vector_type(4))) float  f32x4;

// device-global scratch (no assumptions about ws_size)
__device__ unsigned short g_Wp[KT_N * 8 * 64 * 8];     // 256 KB, MFMA B-frag layout, k-dim i = chan*16+kp
__device__ unsigned short g_featb[NPTS * INF];         // 8 MB, features as bf16
__device__ float g_part[NSETS][2 * OUTF];              // [set][0:128]=sum, [128:256]=sumsq
__device__ float g_scale[OUTF], g_shift[OUTF];

__device__ __forceinline__ unsigned short f2b(float f) {
    union { float f; unsigned int i; } v; v.f = f;
    unsigned int x = v.i;
    return (unsigned short)((x + 0x7fffu + ((x >> 16) & 1u)) >> 16);   // RNE
}
__device__ __forceinline__ unsigned int pk2(float a, float b) {
    return (unsigned int)f2b(a) | ((unsigned int)f2b(b) << 16);
}
__device__ __forceinline__ bf16x8 mk8(unsigned int a, unsigned int b,
                                      unsigned int c, unsigned int d) {
    unsigned int t[4] = {a, b, c, d};
    bf16x8 r; __builtin_memcpy(&r, t, 16); return r;
}

// ---------------- Kernel 0: pack W -> bf16 B-frag (permuted k-enum), feat -> bf16, zero stats
__global__ __launch_bounds__(256) void pack_inputs(const float* __restrict__ W,
                                                   const float* __restrict__ feat) {
    const int b = blockIdx.x, t = threadIdx.x;
    if (b < NSETS) g_part[b][t] = 0.0f;
    if (b < 512) {                      // g_Wp: 131072 entries
        int id = b * 256 + t;
        int j  = id & 7;
        int ln = (id >> 3) & 63;
        int nt = (id >> 9) & 7;
        int kt = id >> 12;              // 0..31
        int i  = kt * 32 + ((ln >> 4) * 8) + j;   // padded k-dim, i = chan*16 + kp
        int kp = i & 15;
        int ch = i >> 4;
        int o  = nt * 16 + (ln & 15);
        g_Wp[id] = (kp < NKP) ? f2b(W[(kp * 64 + ch) * 128 + o]) : (unsigned short)0;
    } else {                            // feat: 1048576 float4s -> bf16 pairs
        int id = (b - 512) * 256 + t;
        const float4 v = ((const float4*)feat)[id];
        uint2 r; r.x = pk2(v.x, v.y); r.y = pk2(v.z, v.w);
        ((uint2*)g_featb)[id] = r;
    }
}

// ---------------- Kernel 1: fused KPConv (both stages MFMA) + BN partial stats (shadow sets)
__global__ __launch_bounds__(256, 4) void kpconv_fused(
        const float* __restrict__ qp,    // [N][3]
        const float* __restrict__ sp,    // [N0][3]
        const int*   __restrict__ nbr,   // [N][32]
        const float* __restrict__ kp,    // [15][3]
        float*       __restrict__ out)   // [N][128] pre-BN x (f32)
{
    // weighted[pl][i] at ((g*PPB + (pl ^ ((g>>3)&7)))*8 + (i&7)), g = i>>3, bf16
    __shared__ __align__(16) unsigned short wlds[128 * PPB * 8];  // 32768 B
    __shared__ float dbuf[4][128][3];                             // 6144 B
    __shared__ int   ibuf[4][128];                                // 2048 B  -> total 40960 B

    const int tid  = threadIdx.x;
    const int lane = tid & 63;
    const int wv   = tid >> 6;
    const int q    = lane >> 4;
    const int c16  = lane & 15;
    const int gp0  = blockIdx.x * PPB + wv * 4;   // wave's first point

    // prologue: all 4 points' neighbor indices + diffs (all 64 lanes busy)
#pragma unroll
    for (int rep = 0; rep < 2; ++rep) {
        const int pt  = rep * 2 + (lane >> 5);
        const int m   = lane & 31;
        const int gpt = gp0 + pt;
        const int idx = nbr[gpt * NNEI + m];
        ibuf[wv][pt * 32 + m] = idx;
        dbuf[wv][pt * 32 + m][0] = sp[idx * 3 + 0] - qp[gpt * 3 + 0];
        dbuf[wv][pt * 32 + m][1] = sp[idx * 3 + 1] - qp[gpt * 3 + 1];
        dbuf[wv][pt * 32 + m][2] = sp[idx * 3 + 2] - qp[gpt * 3 + 2];
    }
    // kernel point per lane (c16 = kp index; 15 = pad -> w = 0)
    float kx, ky, kz;
    if (c16 < NKP) { kx = kp[c16 * 3]; ky = kp[c16 * 3 + 1]; kz = kp[c16 * 3 + 2]; }
    else           { kx = ky = kz = 1.0e6f; }
    // same-wave LDS in-order: no barrier needed before stage A

    // ---------------- Stage A: per point, weighted[16 kp][64 chan] via 4 MFMAs
    // 2-deep software pipeline: pt+1's gathers issued before pt's consumption
    uint2 dcur[8], dnxt[8];
#pragma unroll
    for (int j = 0; j < 8; ++j) {
        const int idx = ibuf[wv][q * 8 + j];
        dcur[j] = *(const uint2*)&g_featb[idx * INF + c16 * 4];
    }

#pragma unroll
    for (int pt = 0; pt < 4; ++pt) {
        const int pl = wv * 4 + pt;

        if (pt < 3) {
#pragma unroll
            for (int j = 0; j < 8; ++j) {
                const int idx = ibuf[wv][(pt + 1) * 32 + q * 8 + j];
                dnxt[j] = *(const uint2*)&g_featb[idx * INF + c16 * 4];
            }
        }

        // A fragment: w[kp = c16][m = q*8+j]
        float w8[8];
#pragma unroll
        for (int j = 0; j < 8; ++j) {
            const int m = pt * 32 + q * 8 + j;
            const float ex = dbuf[wv][m][0] - kx;
            const float ey = dbuf[wv][m][1] - ky;
            const float ez = dbuf[wv][m][2] - kz;
            const float s  = ex * ex + ey * ey + ez * ez;
            const float w  = 1.0f - __builtin_amdgcn_sqrtf(s) * INV_KPE;
            w8[j] = (w > 0.0f) ? w : 0.0f;
        }
        const bf16x8 af = mk8(pk2(w8[0], w8[1]), pk2(w8[2], w8[3]),
                              pk2(w8[4], w8[5]), pk2(w8[6], w8[7]));

        // B fragments from dcur (waits only dcur's loads: vmcnt(8))
        f32x4 acc[4] = {{0.f,0.f,0.f,0.f},{0.f,0.f,0.f,0.f},
                        {0.f,0.f,0.f,0.f},{0.f,0.f,0.f,0.f}};
#pragma unroll
        for (int nt = 0; nt < 4; ++nt) {
            unsigned int dw[4];
#pragma unroll
            for (int p = 0; p < 4; ++p) {
                const unsigned int lo = (nt < 2) ? dcur[2 * p].x     : dcur[2 * p].y;
                const unsigned int hi = (nt < 2) ? dcur[2 * p + 1].x : dcur[2 * p + 1].y;
                dw[p] = (nt & 1) ? ((lo >> 16) | (hi & 0xffff0000u))
                                 : ((lo & 0xffffu) | (hi << 16));
            }
            acc[nt] = __builtin_amdgcn_mfma_f32_16x16x32_bf16(
                af, mk8(dw[0], dw[1], dw[2], dw[3]), acc[nt], 0, 0, 0);
        }

        // C: lane holds weighted[kp = q*4+r][chan = 4*c16+nt] -> i = (4c16+nt)*16 + 4q + r
#pragma unroll
        for (int nt = 0; nt < 4; ++nt) {
            uint2 pv;
            pv.x = pk2(acc[nt][0], acc[nt][1]);
            pv.y = pk2(acc[nt][2], acc[nt][3]);
            const int ibase = (c16 * 4 + nt) * 16 + q * 4;
            const int g   = ibase >> 3;
            const int off = ibase & 7;                 // = 4*(q&1)
            const int plx = pl ^ ((g >> 3) & 7);
            *(uint2*)&wlds[(g * PPB + plx) * 8 + off] = pv;
        }

#pragma unroll
        for (int j = 0; j < 8; ++j) dcur[j] = dnxt[j];
    }
    __syncthreads();

    // ---------------- Stage B: [16 x 1024] @ [1024 x 128]; wave owns 2 n-tiles
    const int nt0 = wv * 2;
    f32x4 a00 = {0.f,0.f,0.f,0.f}, a01 = {0.f,0.f,0.f,0.f};

    for (int kt = 0; kt < KT_N; ++kt) {
        const int g   = kt * 4 + q;
        const int plx = c16 ^ ((g >> 3) & 7);          // A-frag row = point = c16
        const bf16x8 fa  = *(const bf16x8*)&wlds[(g * PPB + plx) * 8];
        const bf16x8 fb0 = *(const bf16x8*)&g_Wp[((kt * 8 + nt0) * 64 + lane) * 8];
        const bf16x8 fb1 = *(const bf16x8*)&g_Wp[((kt * 8 + nt0 + 1) * 64 + lane) * 8];
        a00 = __builtin_amdgcn_mfma_f32_16x16x32_bf16(fa, fb0, a00, 0, 0, 0);
        a01 = __builtin_amdgcn_mfma_f32_16x16x32_bf16(fa, fb1, a01, 0, 0, 0);
    }

    // epilogue: store pre-BN x + per-channel partial stats into shadow set
    const int rb = blockIdx.x * PPB + q * 4;
    const int c0 = nt0 * 16 + c16;
    float s0 = 0.f, q0 = 0.f, s1 = 0.f, q1 = 0.f;
#pragma unroll
    for (int r = 0; r < 4; ++r) {
        const float v0 = a00[r], v1 = a01[r];
        out[(rb + r) * OUTF + c0]      = v0;
        out[(rb + r) * OUTF + c0 + 16] = v1;
        s0 += v0; q0 += v0 * v0;
        s1 += v1; q1 += v1 * v1;
    }
    s0 += __shfl_xor(s0, 16); s0 += __shfl_xor(s0, 32);
    q0 += __shfl_xor(q0, 16); q0 += __shfl_xor(q0, 32);
    s1 += __shfl_xor(s1, 16); s1 += __shfl_xor(s1, 32);
    q1 += __shfl_xor(q1, 16); q1 += __shfl_xor(q1, 32);
    const int set = blockIdx.x & (NSETS - 1);
    if (lane < 16) {
        atomicAdd(&g_part[set][nt0 * 16 + lane],            s0);
        atomicAdd(&g_part[set][OUTF + nt0 * 16 + lane],     q0);
        atomicAdd(&g_part[set][nt0 * 16 + 16 + lane],       s1);
        atomicAdd(&g_part[set][OUTF + nt0 * 16 + 16 + lane], q1);
    }
}

// ---------------- Kernel 2: reduce shadow sets -> per-channel scale/shift
__global__ void bn_scaleshift(const float* __restrict__ gamma,
                              const float* __restrict__ beta) {
    const int o = threadIdx.x;      // 128 threads
    float s = 0.f, qq = 0.f;
    for (int i = 0; i < NSETS; ++i) { s += g_part[i][o]; qq += g_part[i][OUTF + o]; }
    const float inv_n = 1.0f / (float)NPTS;
    const float mean  = s * inv_n;
    const float var   = qq * inv_n - mean * mean;
    const float sc    = gamma[o] * rsqrtf(var + BN_EPS);
    g_scale[o] = sc;
    g_shift[o] = beta[o] - mean * sc;
}

// ---------------- Kernel 3: in-place normalize + LeakyReLU (float4 / thread)
__global__ __launch_bounds__(256) void bn_norm(float* __restrict__ x) {
    const int id   = blockIdx.x * 256 + threadIdx.x;
    const int base = id * 4;
    const int o0   = base & 127;
    float4 v = *(const float4*)&x[base];
    const float4 sc = *(const float4*)&g_scale[o0];
    const float4 sf = *(const float4*)&g_shift[o0];
    float y0 = v.x * sc.x + sf.x;
    float y1 = v.y * sc.y + sf.y;
    float y2 = v.z * sc.z + sf.z;
    float y3 = v.w * sc.w + sf.w;
    y0 = (y0 >= 0.f) ? y0 : NEG_SLOPE * y0;
    y1 = (y1 >= 0.f) ? y1 : NEG_SLOPE * y1;
    y2 = (y2 >= 0.f) ? y2 : NEG_SLOPE * y2;
    y3 = (y3 >= 0.f) ? y3 : NEG_SLOPE * y3;
    float4 res = {y0, y1, y2, y3};
    *(float4*)&x[base] = res;
}

extern "C" void kernel_launch(void* const* d_in, const int* in_sizes, int n_in,
                              void* d_out, int out_size, void* d_ws, size_t ws_size,
                              hipStream_t stream) {
    const float* qp    = (const float*)d_in[0];
    const float* sp    = (const float*)d_in[1];
    const int*   nbr   = (const int*)d_in[2];
    const float* kp    = (const float*)d_in[4];
    const float* W     = (const float*)d_in[5];
    const float* gamma = (const float*)d_in[6];
    const float* beta  = (const float*)d_in[7];
    const float* feat  = (const float*)d_in[3];
    float* out = (float*)d_out;

    pack_inputs<<<512 + 4096, 256, 0, stream>>>(W, feat);
    kpconv_fused<<<NPTS / PPB, 256, 0, stream>>>(qp, sp, nbr, kp, out);
    bn_scaleshift<<<1, 128, 0, stream>>>(gamma, beta);
    bn_norm<<<(NPTS * OUTF) / (256 * 4), 256, 0, stream>>>(out);
}